// Round 1
// baseline (265.423 us; speedup 1.0000x reference)
//
#include <hip/hip_runtime.h>

#define VOCAB   8
#define HIDDEN  768
#define DINUC   192
#define CONCAT  960
#define NDID    17               // 16 dinuc ids + 1 "no dinuc" (last position)
#define NROWS   (VOCAB * NDID)   // 136 distinct output rows
#define SEQ     2048
#define BATCH   32
#define LN_EPS  1e-12f

// ---------------------------------------------------------------------------
// K1: TD[0..7][768]   = token_emb (8x768)  @ W[:, 0:768]^T
//     TD[8..23][768]  = dinuc_emb (16x192) @ W[:, 768:960]^T
// One thread per (row, o). 24*768 = 18432 threads.
// ---------------------------------------------------------------------------
__global__ void k_td(const float* __restrict__ tok,
                     const float* __restrict__ din,
                     const float* __restrict__ W,
                     float* __restrict__ TD) {
    int t = blockIdx.x * blockDim.x + threadIdx.x;
    if (t >= 24 * HIDDEN) return;
    int r = t / HIDDEN;
    int o = t - r * HIDDEN;

    float acc = 0.f;
    if (r < VOCAB) {
        const float4* e = (const float4*)(tok + r * HIDDEN);
        const float4* w = (const float4*)(W + (size_t)o * CONCAT);
        #pragma unroll 4
        for (int i = 0; i < HIDDEN / 4; ++i) {
            float4 ev = e[i], wv = w[i];
            acc += ev.x * wv.x + ev.y * wv.y + ev.z * wv.z + ev.w * wv.w;
        }
    } else {
        const float4* e = (const float4*)(din + (r - VOCAB) * DINUC);
        const float4* w = (const float4*)(W + (size_t)o * CONCAT + HIDDEN);
        #pragma unroll 4
        for (int i = 0; i < DINUC / 4; ++i) {
            float4 ev = e[i], wv = w[i];
            acc += ev.x * wv.x + ev.y * wv.y + ev.z * wv.z + ev.w * wv.w;
        }
    }
    TD[t] = acc;
}

// ---------------------------------------------------------------------------
// K2: table[row=(id*17+did)][o] = LN( T[id] + (did<16 ? D[did] : 0) + bias )
// One block (256 thr = 4 waves) per row; each thread owns 3 outputs.
// Two-pass LN: exact mean, then mean of squared deviations.
// ---------------------------------------------------------------------------
__device__ inline float block_reduce_sum(float s, float* red) {
    int lane = threadIdx.x & 63;
    int wave = threadIdx.x >> 6;
    #pragma unroll
    for (int off = 32; off > 0; off >>= 1) s += __shfl_down(s, off, 64);
    if (lane == 0) red[wave] = s;
    __syncthreads();
    float tot = red[0] + red[1] + red[2] + red[3];
    __syncthreads();
    return tot;
}

__global__ void k_table(const float* __restrict__ TD,
                        const float* __restrict__ bias,
                        const float* __restrict__ gamma,
                        const float* __restrict__ beta,
                        float* __restrict__ table) {
    int row = blockIdx.x;          // 0..135
    int id  = row / NDID;
    int did = row - id * NDID;
    const float* T = TD + id * HIDDEN;
    const float* D = TD + (VOCAB + did) * HIDDEN;
    bool hasd = (did < 16);

    __shared__ float red[4];
    int tid = threadIdx.x;

    float v[3];
    float s = 0.f;
    #pragma unroll
    for (int k = 0; k < 3; ++k) {
        int o = tid + k * 256;
        float x = T[o] + bias[o];
        if (hasd) x += D[o];
        v[k] = x;
        s += x;
    }
    float mu = block_reduce_sum(s, red) * (1.f / HIDDEN);

    float sq = 0.f;
    #pragma unroll
    for (int k = 0; k < 3; ++k) {
        float d = v[k] - mu;
        sq += d * d;
    }
    float var = block_reduce_sum(sq, red) * (1.f / HIDDEN);
    float rstd = rsqrtf(var + LN_EPS);

    #pragma unroll
    for (int k = 0; k < 3; ++k) {
        int o = tid + k * 256;
        table[row * HIDDEN + o] = (v[k] - mu) * rstd * gamma[o] + beta[o];
    }
}

// ---------------------------------------------------------------------------
// K3: broadcast. out[b,s,:] = table[id*17+did]. One float4 per thread.
// block = (192, 4): 4 rows per block, 192 float4 per row. 16384 blocks.
// ---------------------------------------------------------------------------
__global__ void k_bcast(const int* __restrict__ ids,
                        const float* __restrict__ table,
                        float4* __restrict__ out) {
    int row = blockIdx.x * 4 + threadIdx.y;     // 0 .. 65535 (= b*SEQ + s)
    int s   = row & (SEQ - 1);
    int a   = ids[row];
    int did;
    if (s == SEQ - 1) {
        did = 16;                               // padded position: no dinuc
    } else {
        int b = ids[row + 1];
        bool valid = (a >= 4) & (a <= 7) & (b >= 4) & (b <= 7);
        did = valid ? ((a - 4) * 4 + (b - 4)) : 0;
    }
    const float4* src = (const float4*)(table + (a * NDID + did) * HIDDEN);
    out[(size_t)row * (HIDDEN / 4) + threadIdx.x] = src[threadIdx.x];
}

// ---------------------------------------------------------------------------
extern "C" void kernel_launch(void* const* d_in, const int* in_sizes, int n_in,
                              void* d_out, int out_size, void* d_ws, size_t ws_size,
                              hipStream_t stream) {
    const int*   ids   = (const int*)d_in[0];
    const float* tok   = (const float*)d_in[1];
    const float* din   = (const float*)d_in[2];
    const float* W     = (const float*)d_in[3];
    const float* bias  = (const float*)d_in[4];
    const float* gamma = (const float*)d_in[5];
    const float* beta  = (const float*)d_in[6];

    float* table = (float*)d_ws;                 // 136*768 floats = 417792 B
    float* TD    = table + NROWS * HIDDEN;       //  24*768 floats =  73728 B

    k_td   <<<(24 * HIDDEN + 255) / 256, 256, 0, stream>>>(tok, din, W, TD);
    k_table<<<NROWS, 256, 0, stream>>>(TD, bias, gamma, beta, table);
    k_bcast<<<(BATCH * SEQ) / 4, dim3(192, 4), 0, stream>>>(ids, table, (float4*)d_out);
}